// Round 7
// baseline (209.894 us; speedup 1.0000x reference)
//
#include <hip/hip_runtime.h>

#define NL 100
#define BB 8
#define HH 1024
#define NPIX (1024 * 1024)
#define EPSF 1e-7f
#define NBLK 128           // stats blocks per batch (8 rows each) -- proven
#define LGX 256            // loss blocks per batch (4 rows each)  -- proven
#define NLOSS (LGX * BB)   // 2048

typedef float f4 __attribute__((ext_vector_type(4)));

// ws word offsets. End = 2,612,384 words = 10,449,536 B -- below the proven
// workspace ceiling (10,457,664 B; round-4/5 exceeded it and the container
// died). Header (ACC/TKT) zeroed by k_stats block(0,0); consumed only a
// kernel boundary later (proven visibility mechanism).
#define OFF_ACC  0                                  // float loss accumulator
#define OFF_TKT  1                                  // u32 loss ticket
#define OFF_TAB  16                                 // f4[BB*NL] (byte 64, 16B-aligned)
#define OFF_CNT0 (OFF_TAB + 4 * BB * NL)            // u32[BB]
#define OFF_M8   (OFF_CNT0 + BB + 8)                // u32[BB*NPIX/4] (16B-aligned)
#define OFF_PART (OFF_M8 + BB * (NPIX / 4))         // u32[5*NBLK*BB*NL], [v][blk][b][l]

__device__ __forceinline__ int part_idx(int v, int blk, int b, int l) {
    return ((v * NBLK + blk) * BB + b) * NL + l;    // l contiguous -> coalesced
}

// K1: EXACT proven stats kernel (round-0/round-6): wave = 2 rows, packed
// cnt<<21|sx LDS tables, one flush per 2 rows, plain coalesced partial stores.
// Block(0,0) zeroes the 2-word header (kernel-boundary visible to k_loss).
__global__ __launch_bounds__(256) void k_stats(const int* __restrict__ mask,
                                               unsigned* __restrict__ wsu) {
    __shared__ unsigned s_cs[4][2][NL];   // per wave, per row: cnt<<21 | sum_x
    __shared__ unsigned s_mx[4][NL];
    __shared__ unsigned g_cnt[NL], g_sx[NL], g_sy[NL], g_mx[NL], g_my[NL];
    unsigned* part = wsu + OFF_PART;
    unsigned* m8   = wsu + OFF_M8;
    const int b    = blockIdx.y;
    const int blk  = blockIdx.x;
    const int wv   = threadIdx.x >> 6;
    const int lane = threadIdx.x & 63;
    if (blk == 0 && b == 0 && threadIdx.x == 0) {
        wsu[OFF_ACC] = 0u;
        wsu[OFF_TKT] = 0u;
    }
    for (int i = threadIdx.x; i < NL; i += 256) {
        g_cnt[i] = 0u; g_sx[i] = 0u; g_sy[i] = 0u; g_mx[i] = 0u; g_my[i] = 0u;
    }
    for (int i = lane; i < 2 * NL; i += 64) s_cs[wv][0][i] = 0u;   // covers [0] and [1]
    for (int i = lane; i < NL; i += 64) s_mx[wv][i] = 0u;
    __syncthreads();

    const int4* m4  = (const int4*)(mask + (size_t)b * NPIX);
    unsigned*   m8b = m8 + (size_t)b * (NPIX / 4);
    const int y0 = blk * 8 + wv * 2;

    int4 R[2][4];
#pragma unroll
    for (int r = 0; r < 2; ++r)
#pragma unroll
        for (int it = 0; it < 4; ++it)
            R[r][it] = m4[(y0 + r) * 256 + it * 64 + lane];

#pragma unroll
    for (int r = 0; r < 2; ++r) {
        unsigned* tp = &s_cs[wv][r][0];
        unsigned* mp = &s_mx[wv][0];
        const int y = y0 + r;
#pragma unroll
        for (int it = 0; it < 4; ++it) {
            const int4 mv = R[r][it];
            const int c4 = it * 64 + lane;
            const unsigned v0 = (1u << 21) + (unsigned)(c4 << 2);
            atomicAdd(tp + mv.x, v0);      atomicMax(mp + mv.x, v0);
            atomicAdd(tp + mv.y, v0 + 1u); atomicMax(mp + mv.y, v0 + 1u);
            atomicAdd(tp + mv.z, v0 + 2u); atomicMax(mp + mv.z, v0 + 2u);
            atomicAdd(tp + mv.w, v0 + 3u); atomicMax(mp + mv.w, v0 + 3u);
            m8b[y * 256 + c4] = (unsigned)mv.x | ((unsigned)mv.y << 8) |
                                ((unsigned)mv.z << 16) | ((unsigned)mv.w << 24);
        }
    }
    // single flush for both rows of this wave (wave-private tables: no barrier)
    for (int e = lane; e < NL; e += 64) {
        const unsigned cs0 = s_cs[wv][0][e];
        const unsigned cs1 = s_cs[wv][1][e];
        const unsigned c0 = cs0 >> 21, c1 = cs1 >> 21;
        const unsigned cnt = c0 + c1;
        if (cnt) {
            atomicAdd(&g_cnt[e], cnt);
            atomicAdd(&g_sx[e], (cs0 & 0x1FFFFFu) + (cs1 & 0x1FFFFFu));
            atomicAdd(&g_sy[e], c0 * (unsigned)y0 + c1 * (unsigned)(y0 + 1));
            atomicMax(&g_my[e], c1 ? (unsigned)(y0 + 1) : (unsigned)y0);
            atomicMax(&g_mx[e], s_mx[wv][e] & 0x1FFFFFu);
        }
    }
    __syncthreads();
    for (int e = threadIdx.x; e < NL; e += 256) {
        part[part_idx(0, blk, b, e)] = g_cnt[e];
        part[part_idx(1, blk, b, e)] = g_sx[e];
        part[part_idx(2, blk, b, e)] = g_sy[e];
        part[part_idx(3, blk, b, e)] = g_mx[e];
        part[part_idx(4, blk, b, e)] = g_my[e];
    }
}

// K2: single-kernel table build. grid(BB) x 512: thread t=(v,l) reduces all
// 128 block-slots (coalesced 400B runs, unroll-4, 8 waves -> latency hidden),
// LDS-combine, then t<100 computes the f4 table + cnt0. Plain stores: consumed
// by k_loss across a kernel boundary (proven round-0 mechanism).
__global__ __launch_bounds__(512) void k_final(unsigned* __restrict__ wsu) {
    __shared__ unsigned s_st[5][NL];
    const unsigned* part = wsu + OFF_PART;
    const int b = blockIdx.x;
    const int t = threadIdx.x;
    if (t < 5 * NL) {
        const int v = t / NL;
        const int l = t - v * NL;
        unsigned s = 0u, m = 0u;
#pragma unroll 4
        for (int k = 0; k < NBLK; ++k) {
            const unsigned u = part[part_idx(v, k, b, l)];
            s += u; m = max(m, u);
        }
        s_st[v][l] = (v >= 3) ? m : s;
    }
    __syncthreads();
    if (t < NL) {   // proven k_final math
        const unsigned cnt = s_st[0][t];
        const float sc = (float)(cnt ? cnt : 1u);
        const float xc = (float)s_st[1][t] / sc;
        const float yc = (float)s_st[2][t] / sc;
        float fmx = (float)s_st[3][t] - xc; if (fmx < 0.0f) fmx = 0.0f;
        float fmy = (float)s_st[4][t] - yc; if (fmy < 0.0f) fmy = 0.0f;
        f4 e;
        e.x = xc;
        e.y = yc;
        e.z = (fmx == 0.0f) ? 1.0f : 1.0f / fmx;
        e.w = (fmy == 0.0f) ? 1.0f : 1.0f / fmy;
        ((f4*)(wsu + OFF_TAB))[b * NL + t] = e;
        if (t == 0) wsu[OFF_CNT0 + b] = cnt;
    }
}

// K3: proven round-0 loss kernel (2-load head: streaming starts immediately;
// 16 px/thread; hoisted NT loads; packed NT f4 stores) + proven round-6
// fence-free atomic+ticket tail (replaces lp[]+k_sum).
__global__ __launch_bounds__(256, 4) void k_loss(const float* __restrict__ pred,
                                                 const float* __restrict__ ig,
                                                 unsigned* __restrict__ wsu,
                                                 float* __restrict__ out) {
    __shared__ f4 s_tab[NL];
    __shared__ unsigned s_c0[BB];
    __shared__ float s_part[4];
    const unsigned* m8 = wsu + OFF_M8;
    const int b = blockIdx.y;
    const int tid = threadIdx.x;
    for (int i = tid; i < NL; i += 256)
        s_tab[i] = ((const f4*)(wsu + OFF_TAB))[b * NL + i];
    if (tid < BB) s_c0[tid] = wsu[OFF_CNT0 + tid];
    __syncthreads();
    float bgc = 0.0f;
#pragma unroll
    for (int i = 0; i < BB; ++i) bgc += (float)s_c0[i];
    const float n = (float)BB * (float)NPIX;
    const float inv_bg = 1.0f / (bgc + EPSF * n);
    const float inv_fg = 1.0f / ((n - bgc) + EPSF * n);

    const unsigned* m8b = m8 + (size_t)b * (NPIX / 4);
    const f4* ig4 = (const f4*)(ig + (size_t)b * NPIX);
    const f4* px4 = (const f4*)(pred + (size_t)(2 * b) * NPIX);
    const f4* py4 = (const f4*)(pred + (size_t)(2 * b + 1) * NPIX);
    f4* gx4 = (f4*)(out + 1 + (size_t)(2 * b) * NPIX);   // +4B misaligned: HW-ok (proven)
    f4* gy4 = (f4*)(out + 1 + (size_t)(2 * b + 1) * NPIX);

    const int base = blockIdx.x * 1024;
    unsigned M8[4]; f4 IV[4], PX[4], PY[4];
#pragma unroll
    for (int it = 0; it < 4; ++it) {
        const int i4 = base + it * 256 + tid;
        M8[it] = m8b[i4];
        IV[it] = __builtin_nontemporal_load(&ig4[i4]);
        PX[it] = __builtin_nontemporal_load(&px4[i4]);
        PY[it] = __builtin_nontemporal_load(&py4[i4]);
    }

    float acc = 0.0f;
#pragma unroll
    for (int it = 0; it < 4; ++it) {
        const int i4 = base + it * 256 + tid;
        const int p  = i4 << 2;
        const float x0 = (float)(p & (HH - 1));
        const float y  = (float)(p >> 10);
        const float* igs = (const float*)&IV[it];
        const float* pxs = (const float*)&PX[it];
        const float* pys = (const float*)&PY[it];
        f4 gxv, gyv;
        float* gxa = (float*)&gxv;
        float* gya = (float*)&gyv;
#pragma unroll
        for (int j = 0; j < 4; ++j) {
            const int m = (int)((M8[it] >> (8 * j)) & 255u);
            const f4 t = s_tab[m];
            const float fgf = (m != 0) ? 1.0f : 0.0f;
            const float gx = (x0 + (float)j - t.x) * t.z * fgf;
            const float gy = (y - t.y) * t.w * fgf;
            const float w  = ((m != 0) ? inv_fg : inv_bg) * igs[j];
            const float dx = pxs[j] - gx;
            const float dy = pys[j] - gy;
            const float ax = fabsf(dx), ay = fabsf(dy);
            acc += ((ax < 1.0f) ? 0.5f * dx * dx : ax - 0.5f) * w
                 + ((ay < 1.0f) ? 0.5f * dy * dy : ay - 0.5f) * w;
            gxa[j] = gx;
            gya[j] = gy;
        }
        __builtin_nontemporal_store(gxv, &gx4[i4]);
        __builtin_nontemporal_store(gyv, &gy4[i4]);
    }
    // wave + block reduction, then proven fence-free ticket finish
#pragma unroll
    for (int off = 32; off > 0; off >>= 1) acc += __shfl_down(acc, off, 64);
    const int lane = tid & 63, wv = tid >> 6;
    if (lane == 0) s_part[wv] = acc;
    __syncthreads();
    if (tid == 0) {
        const float s = s_part[0] + s_part[1] + s_part[2] + s_part[3];
        const float old = atomicAdd((float*)wsu + OFF_ACC, s);
        // consume the return: RMW complete at the coherent point before ticket
        asm volatile("" : : "v"(old) : "memory");
        const unsigned t = atomicAdd(wsu + OFF_TKT, 1u);
        if (t == NLOSS - 1) {
            out[0] = atomicAdd((float*)wsu + OFF_ACC, 0.0f);  // coherent read (proven)
        }
    }
}

extern "C" void kernel_launch(void* const* d_in, const int* in_sizes, int n_in,
                              void* d_out, int out_size, void* d_ws, size_t ws_size,
                              hipStream_t stream) {
    const float* pred = (const float*)d_in[0];
    const int*   mask = (const int*)d_in[1];
    const float* ig   = (const float*)d_in[2];
    float* out = (float*)d_out;
    unsigned* wsu = (unsigned*)d_ws;

    k_stats<<<dim3(NBLK, BB), 256, 0, stream>>>(mask, wsu);
    k_final<<<BB, 512, 0, stream>>>(wsu);
    k_loss<<<dim3(LGX, BB), 256, 0, stream>>>(pred, ig, wsu, out);
}

// Round 8
// 177.440 us; speedup vs baseline: 1.1829x; 1.1829x over previous
//
#include <hip/hip_runtime.h>

#define NL 100
#define BB 8
#define HH 1024
#define NPIX (1024 * 1024)
#define EPSF 1e-7f
#define NBLK 128           // stats blocks per batch (8 rows each) -- proven
#define LGX 256            // loss blocks per batch (4 rows each)  -- proven

typedef float f4 __attribute__((ext_vector_type(4)));

// ws word offsets. Accumulator/ticket lines are 128B-separated to avoid
// same-line RMW serialization (round-7 lesson: 4096 same-line RMWs = ~27us).
// Footprint ends at 2,105,488 words = 8,421,952 B -- well under the proven
// 10,457,664 B workspace ceiling (rounds 4/5 died above it).
// Words [0, 5024) zeroed by a 20KB memset each launch (poisoned workspace).
#define OFF_GACC 0                       // f32 global loss acc   (line 0)
#define OFF_GTKT 1                       // u32 global ticket     (line 0)
#define OFF_BACC 64                      // f32 batch acc b: 64+b*32  (own line)
#define OFF_BTKT 320                     // u32 batch tkt b: 320+b*32 (own line)
#define OFF_STKT 576                     // u32 stats tkt b: 576+b*32 (own line)
#define OFF_GST  1024                    // u32[5][BB][NL] = 4000 device-scope stats
#define OFF_TAB  5120                    // f4[BB*NL] (byte 20480, 16B-aligned)
#define OFF_CNT0 8320                    // u32[BB]
#define OFF_M8   8336                    // u32[BB*NPIX/4] (byte 33344, 16B-aligned)
#define ZERO_BYTES 20480                 // covers [0, 5120) words

__device__ __forceinline__ int gst_idx(int v, int b, int l) {
    return (v * BB + b) * NL + l;
}

// K1: proven stats body (wave = 2 rows, packed cnt<<21|sx LDS tables, one
// flush per 2 rows) + device-scope atomic flush (replaces PART stores) +
// per-batch ticket; last block of each batch atomically reads the accumulated
// 500 words and builds the f4 table + cnt0 (absorbs k_final). All cross-block
// traffic uses the round-6/7-proven atomic-write/atomic-read primitive.
__global__ __launch_bounds__(256) void k_stats(const int* __restrict__ mask,
                                               unsigned* __restrict__ wsu) {
    __shared__ unsigned s_cs[4][2][NL];   // per wave, per row: cnt<<21 | sum_x
    __shared__ unsigned s_mx[4][NL];
    __shared__ unsigned g_cnt[NL], g_sx[NL], g_sy[NL], g_mx[NL], g_my[NL];
    __shared__ unsigned s_fin[5][NL];
    __shared__ int s_last;
    unsigned* gst = wsu + OFF_GST;
    unsigned* m8  = wsu + OFF_M8;
    const int b    = blockIdx.y;
    const int blk  = blockIdx.x;
    const int wv   = threadIdx.x >> 6;
    const int lane = threadIdx.x & 63;
    for (int i = threadIdx.x; i < NL; i += 256) {
        g_cnt[i] = 0u; g_sx[i] = 0u; g_sy[i] = 0u; g_mx[i] = 0u; g_my[i] = 0u;
    }
    for (int i = lane; i < 2 * NL; i += 64) s_cs[wv][0][i] = 0u;   // covers [0] and [1]
    for (int i = lane; i < NL; i += 64) s_mx[wv][i] = 0u;
    __syncthreads();

    const int4* m4  = (const int4*)(mask + (size_t)b * NPIX);
    unsigned*   m8b = m8 + (size_t)b * (NPIX / 4);
    const int y0 = blk * 8 + wv * 2;

    int4 R[2][4];
#pragma unroll
    for (int r = 0; r < 2; ++r)
#pragma unroll
        for (int it = 0; it < 4; ++it)
            R[r][it] = m4[(y0 + r) * 256 + it * 64 + lane];

#pragma unroll
    for (int r = 0; r < 2; ++r) {
        unsigned* tp = &s_cs[wv][r][0];
        unsigned* mp = &s_mx[wv][0];
        const int y = y0 + r;
#pragma unroll
        for (int it = 0; it < 4; ++it) {
            const int4 mv = R[r][it];
            const int c4 = it * 64 + lane;
            const unsigned v0 = (1u << 21) + (unsigned)(c4 << 2);
            atomicAdd(tp + mv.x, v0);      atomicMax(mp + mv.x, v0);
            atomicAdd(tp + mv.y, v0 + 1u); atomicMax(mp + mv.y, v0 + 1u);
            atomicAdd(tp + mv.z, v0 + 2u); atomicMax(mp + mv.z, v0 + 2u);
            atomicAdd(tp + mv.w, v0 + 3u); atomicMax(mp + mv.w, v0 + 3u);
            m8b[y * 256 + c4] = (unsigned)mv.x | ((unsigned)mv.y << 8) |
                                ((unsigned)mv.z << 16) | ((unsigned)mv.w << 24);
        }
    }
    // single flush for both rows of this wave (wave-private tables: no barrier)
    for (int e = lane; e < NL; e += 64) {
        const unsigned cs0 = s_cs[wv][0][e];
        const unsigned cs1 = s_cs[wv][1][e];
        const unsigned c0 = cs0 >> 21, c1 = cs1 >> 21;
        const unsigned cnt = c0 + c1;
        if (cnt) {
            atomicAdd(&g_cnt[e], cnt);
            atomicAdd(&g_sx[e], (cs0 & 0x1FFFFFu) + (cs1 & 0x1FFFFFu));
            atomicAdd(&g_sy[e], c0 * (unsigned)y0 + c1 * (unsigned)(y0 + 1));
            atomicMax(&g_my[e], c1 ? (unsigned)(y0 + 1) : (unsigned)y0);
            atomicMax(&g_mx[e], s_mx[wv][e] & 0x1FFFFFu);
        }
    }
    __syncthreads();
    // flush to device-scope accumulators; consume every return so all RMWs
    // are complete at the coherent point before the ticket (proven primitive).
    unsigned dummy = 0u;
    for (int t = threadIdx.x; t < 5 * NL; t += 256) {
        const int v = t / NL;
        const int l = t - v * NL;
        const unsigned u = (v == 0) ? g_cnt[l] : (v == 1) ? g_sx[l]
                         : (v == 2) ? g_sy[l] : (v == 3) ? g_mx[l] : g_my[l];
        if (u) {
            dummy += (v < 3) ? atomicAdd(&gst[gst_idx(v, b, l)], u)
                             : atomicMax(&gst[gst_idx(v, b, l)], u);
        }
    }
    asm volatile("" : : "v"(dummy));
    if (threadIdx.x == 0) {
        const unsigned old = atomicAdd(wsu + OFF_STKT + b * 32, 1u);
        s_last = (old == NBLK - 1) ? 1 : 0;
    }
    __syncthreads();
    if (!s_last) return;
    // last block of this batch: atomic-read the accumulated stats (coherent),
    // build the table, plain-store (k_loss reads across the kernel boundary).
    for (int t = threadIdx.x; t < 5 * NL; t += 256) {
        const int v = t / NL;
        const int l = t - v * NL;
        s_fin[v][l] = atomicAdd(&gst[gst_idx(v, b, l)], 0u);
    }
    __syncthreads();
    if (threadIdx.x < NL) {
        const int l = threadIdx.x;
        const unsigned cnt = s_fin[0][l];
        const float sc = (float)(cnt ? cnt : 1u);
        const float xc = (float)s_fin[1][l] / sc;
        const float yc = (float)s_fin[2][l] / sc;
        float fmx = (float)s_fin[3][l] - xc; if (fmx < 0.0f) fmx = 0.0f;
        float fmy = (float)s_fin[4][l] - yc; if (fmy < 0.0f) fmy = 0.0f;
        f4 e;
        e.x = xc;
        e.y = yc;
        e.z = (fmx == 0.0f) ? 1.0f : 1.0f / fmx;
        e.w = (fmy == 0.0f) ? 1.0f : 1.0f / fmy;
        ((f4*)(wsu + OFF_TAB))[b * NL + l] = e;
        if (l == 0) wsu[OFF_CNT0 + b] = cnt;
    }
}

// K2: proven round-0 loss body (streaming starts in the first instructions;
// 16 px/thread; hoisted NT loads; packed NT f4 stores) + HIERARCHICAL
// fence-free ticket tail: per-batch acc/ticket on private cache lines
// (~256 RMWs/line vs round-7's 4096 -> the ~27us contention stall gone).
__global__ __launch_bounds__(256, 4) void k_loss(const float* __restrict__ pred,
                                                 const float* __restrict__ ig,
                                                 unsigned* __restrict__ wsu,
                                                 float* __restrict__ out) {
    __shared__ f4 s_tab[NL];
    __shared__ unsigned s_c0[BB];
    __shared__ float s_part[4];
    const unsigned* m8 = wsu + OFF_M8;
    const int b = blockIdx.y;
    const int tid = threadIdx.x;
    for (int i = tid; i < NL; i += 256)
        s_tab[i] = ((const f4*)(wsu + OFF_TAB))[b * NL + i];
    if (tid < BB) s_c0[tid] = wsu[OFF_CNT0 + tid];
    __syncthreads();
    float bgc = 0.0f;
#pragma unroll
    for (int i = 0; i < BB; ++i) bgc += (float)s_c0[i];
    const float n = (float)BB * (float)NPIX;
    const float inv_bg = 1.0f / (bgc + EPSF * n);
    const float inv_fg = 1.0f / ((n - bgc) + EPSF * n);

    const unsigned* m8b = m8 + (size_t)b * (NPIX / 4);
    const f4* ig4 = (const f4*)(ig + (size_t)b * NPIX);
    const f4* px4 = (const f4*)(pred + (size_t)(2 * b) * NPIX);
    const f4* py4 = (const f4*)(pred + (size_t)(2 * b + 1) * NPIX);
    f4* gx4 = (f4*)(out + 1 + (size_t)(2 * b) * NPIX);   // +4B misaligned: HW-ok (proven)
    f4* gy4 = (f4*)(out + 1 + (size_t)(2 * b + 1) * NPIX);

    const int base = blockIdx.x * 1024;
    unsigned M8[4]; f4 IV[4], PX[4], PY[4];
#pragma unroll
    for (int it = 0; it < 4; ++it) {
        const int i4 = base + it * 256 + tid;
        M8[it] = m8b[i4];
        IV[it] = __builtin_nontemporal_load(&ig4[i4]);
        PX[it] = __builtin_nontemporal_load(&px4[i4]);
        PY[it] = __builtin_nontemporal_load(&py4[i4]);
    }

    float acc = 0.0f;
#pragma unroll
    for (int it = 0; it < 4; ++it) {
        const int i4 = base + it * 256 + tid;
        const int p  = i4 << 2;
        const float x0 = (float)(p & (HH - 1));
        const float y  = (float)(p >> 10);
        const float* igs = (const float*)&IV[it];
        const float* pxs = (const float*)&PX[it];
        const float* pys = (const float*)&PY[it];
        f4 gxv, gyv;
        float* gxa = (float*)&gxv;
        float* gya = (float*)&gyv;
#pragma unroll
        for (int j = 0; j < 4; ++j) {
            const int m = (int)((M8[it] >> (8 * j)) & 255u);
            const f4 t = s_tab[m];
            const float fgf = (m != 0) ? 1.0f : 0.0f;
            const float gx = (x0 + (float)j - t.x) * t.z * fgf;
            const float gy = (y - t.y) * t.w * fgf;
            const float w  = ((m != 0) ? inv_fg : inv_bg) * igs[j];
            const float dx = pxs[j] - gx;
            const float dy = pys[j] - gy;
            const float ax = fabsf(dx), ay = fabsf(dy);
            acc += ((ax < 1.0f) ? 0.5f * dx * dx : ax - 0.5f) * w
                 + ((ay < 1.0f) ? 0.5f * dy * dy : ay - 0.5f) * w;
            gxa[j] = gx;
            gya[j] = gy;
        }
        __builtin_nontemporal_store(gxv, &gx4[i4]);
        __builtin_nontemporal_store(gyv, &gy4[i4]);
    }
    // wave + block reduction, then hierarchical fence-free ticket finish
#pragma unroll
    for (int off = 32; off > 0; off >>= 1) acc += __shfl_down(acc, off, 64);
    const int lane = tid & 63, wv = tid >> 6;
    if (lane == 0) s_part[wv] = acc;
    __syncthreads();
    if (tid == 0) {
        const float s = s_part[0] + s_part[1] + s_part[2] + s_part[3];
        float* bacc = (float*)wsu + OFF_BACC + b * 32;
        const float old = atomicAdd(bacc, s);
        asm volatile("" : : "v"(old));                       // RMW complete
        const unsigned t = atomicAdd(wsu + OFF_BTKT + b * 32, 1u);
        if (t == LGX - 1) {                    // last block of this batch
            const float tb = atomicAdd(bacc, 0.0f);          // coherent read
            const float o2 = atomicAdd((float*)wsu + OFF_GACC, tb);
            asm volatile("" : : "v"(o2));                    // RMW complete
            const unsigned t2 = atomicAdd(wsu + OFF_GTKT, 1u);
            if (t2 == BB - 1)
                out[0] = atomicAdd((float*)wsu + OFF_GACC, 0.0f);
        }
    }
}

extern "C" void kernel_launch(void* const* d_in, const int* in_sizes, int n_in,
                              void* d_out, int out_size, void* d_ws, size_t ws_size,
                              hipStream_t stream) {
    const float* pred = (const float*)d_in[0];
    const int*   mask = (const int*)d_in[1];
    const float* ig   = (const float*)d_in[2];
    float* out = (float*)d_out;
    unsigned* wsu = (unsigned*)d_ws;

    (void)hipMemsetAsync(d_ws, 0, ZERO_BYTES, stream);   // zero accs + tickets
    k_stats<<<dim3(NBLK, BB), 256, 0, stream>>>(mask, wsu);
    k_loss<<<dim3(LGX, BB), 256, 0, stream>>>(pred, ig, wsu, out);
}